// Round 16
// baseline (44.440 us; speedup 1.0000x reference)
//
#include <hip/hip_runtime.h>
#include <hip/hip_bf16.h>

#define SEQ    2048
#define NHEAD  16
#define RPH    512          // rows per head = B*D
#define BK     64
#define NTH    256          // 4 waves: wave tb = col quarter of the quad

#define WSTRIDE 2184        // elems per wrev copy; 2184 % 64 == 8 (bank spread)
#define ABUF_E  2048        // elems per A buffer (32 rows x 64 cols bf16)
#define WCOP_E  (4 * ABUF_E)             // wcop after the FOUR A buffers
#define TOT_E   (WCOP_E + 8 * WSTRIDE)   // 8192 + 17472 = 25664 elems (51328 B)
// wbase staging (guard 0..7, data 8..2055, zero pad 2056..2215) aliases abufs

typedef float  f32x4  __attribute__((ext_vector_type(4)));
typedef __bf16 bf16x8 __attribute__((ext_vector_type(8)));

struct PF { float4 v0, v1; };

__device__ __forceinline__ unsigned f2bf(float f) {
    union { __hip_bfloat16 h; unsigned short u; } cv;
    cv.h = __float2bfloat16(f);
    return (unsigned)cv.u;
}

__device__ __forceinline__ uint4 pack8u(float4 a, float4 b) {
    union { bf16x8 v; uint4 u; } r;
    r.v[0] = (__bf16)a.x; r.v[1] = (__bf16)a.y;
    r.v[2] = (__bf16)a.z; r.v[3] = (__bf16)a.w;
    r.v[4] = (__bf16)b.x; r.v[5] = (__bf16)b.y;
    r.v[6] = (__bf16)b.z; r.v[7] = (__bf16)b.w;
    return r.u;
}

#define MFMA16(a, b, c) __builtin_amdgcn_mfma_f32_16x16x32_bf16((a), (b), (c), 0, 0, 0)

// Load this thread's 1 staged row x 8 cols fp32 of chunk CH
// (block stages 32 rows: tid>>3 = row, (tid&7)*8 = col base).
#define LOADPF(P, CH)                                                         \
  { const float* g_ = Xp + (size_t)(CH) * BK;                                 \
    P.v0 = *(const float4*)g_;                                                \
    P.v1 = *(const float4*)(g_ + 4); }

// Pack+write this thread's staged row-slice into buffer AB (XOR-swizzled).
#define WRITEA(AB, P)  { *(uint4*)((AB) + wb0) = pack8u(P.v0, P.v1); }

// One K=32 step: A frags from shared LDS buf ABC, B words from the sliding
// 16-slot window bw at slot (P + 2*KS - c) & 15 (all compile-time).
#define KSTEPQ(ABC, KS, P)                                                    \
  { const int kb_ = (64 * (KS) + kq16) ^ swz;                                 \
    bf16x8 af0 = *(const bf16x8*)((ABC) + Arow0 + kb_);                       \
    bf16x8 af1 = *(const bf16x8*)((ABC) + Arow1 + kb_);                       \
    acc[0][0] = MFMA16(af0, bw[((P)+2*(KS)-0)&15], acc[0][0]);                \
    acc[1][0] = MFMA16(af1, bw[((P)+2*(KS)-0)&15], acc[1][0]);                \
    acc[0][1] = MFMA16(af0, bw[((P)+2*(KS)-1)&15], acc[0][1]);                \
    acc[1][1] = MFMA16(af1, bw[((P)+2*(KS)-1)&15], acc[1][1]);                \
    acc[0][2] = MFMA16(af0, bw[((P)+2*(KS)-2)&15], acc[0][2]);                \
    acc[1][2] = MFMA16(af1, bw[((P)+2*(KS)-2)&15], acc[1][2]);                \
    acc[0][3] = MFMA16(af0, bw[((P)+2*(KS)-3)&15], acc[0][3]);                \
    acc[1][3] = MFMA16(af1, bw[((P)+2*(KS)-3)&15], acc[1][3]);                \
    acc[0][4] = MFMA16(af0, bw[((P)+2*(KS)-4)&15], acc[0][4]);                \
    acc[1][4] = MFMA16(af1, bw[((P)+2*(KS)-4)&15], acc[1][4]);                \
    acc[0][5] = MFMA16(af0, bw[((P)+2*(KS)-5)&15], acc[0][5]);                \
    acc[1][5] = MFMA16(af1, bw[((P)+2*(KS)-5)&15], acc[1][5]);                \
    acc[0][6] = MFMA16(af0, bw[((P)+2*(KS)-6)&15], acc[0][6]);                \
    acc[1][6] = MFMA16(af1, bw[((P)+2*(KS)-6)&15], acc[1][6]);                \
    acc[0][7] = MFMA16(af0, bw[((P)+2*(KS)-7)&15], acc[0][7]);                \
    acc[1][7] = MFMA16(af1, bw[((P)+2*(KS)-7)&15], acc[1][7]); }

// One SUPERCHUNK = chunks CH, CH+1, ONE barrier. Entry: C0,C1 hold A(CH),
// A(CH+1) (visible), pfA = x(CH+2), pfB = x(CH+3), window holds words
// 4CH-7..4CH. Stages CH+2,CH+3 into N0,N1; refills 8 window words; the
// single lgkm-drain+barrier covers all of it (global loads stay in flight).
#define SUPER(CH, P, C0, C1, N0, N1)                                          \
  {                                                                           \
    WRITEA(N0, pfA);                                                          \
    WRITEA(N1, pfB);                                                          \
    if ((CH) + 4 < nch) LOADPF(pfA, (CH) + 4);                                \
    if ((CH) + 5 < nch) LOADPF(pfB, (CH) + 5);                                \
    if ((CH) < nchw) {                                                        \
      __builtin_amdgcn_s_setprio(1);                                          \
      KSTEPQ(C0, 0, P);                                                       \
      bw[((P)+1)&15] = *(const bf16x8*)(wcB + 64 * (CH) + 16);                \
      bw[((P)+2)&15] = *(const bf16x8*)(wcB + 64 * (CH) + 32);                \
      KSTEPQ(C0, 1, P);                                                       \
      __builtin_amdgcn_s_setprio(0);                                          \
    }                                                                         \
    if ((CH) + 1 < nchw) {                                                    \
      bw[((P)+3)&15] = *(const bf16x8*)(wcB + 64 * (CH) + 48);                \
      bw[((P)+4)&15] = *(const bf16x8*)(wcB + 64 * (CH) + 64);                \
      __builtin_amdgcn_s_setprio(1);                                          \
      KSTEPQ(C1, 0, (P) + 4);                                                 \
      bw[((P)+5)&15] = *(const bf16x8*)(wcB + 64 * (CH) + 80);                \
      bw[((P)+6)&15] = *(const bf16x8*)(wcB + 64 * (CH) + 96);                \
      KSTEPQ(C1, 1, (P) + 4);                                                 \
      __builtin_amdgcn_s_setprio(0);                                          \
    }                                                                         \
    if ((CH) + 2 < nchw) {                                                    \
      bw[((P)+7)&15] = *(const bf16x8*)(wcB + 64 * (CH) + 112);               \
      bw[((P)+8)&15] = *(const bf16x8*)(wcB + 64 * (CH) + 128);               \
    }                                                                         \
    asm volatile("s_waitcnt lgkmcnt(0)\n\ts_barrier" ::: "memory");           \
  }

__global__ __launch_bounds__(NTH, 2) void mixer_kernel(
    const float* __restrict__ x, const float* __restrict__ wgt,
    const float* __restrict__ bias, float* __restrict__ out)
{
    __shared__ unsigned short smem[TOT_E] __attribute__((aligned(16)));
    char* ab0 = (char*)smem;                    // A buffers (chunks mod 4)
    char* ab1 = (char*)smem + ABUF_E * 2;
    char* ab2 = (char*)smem + ABUF_E * 4;
    char* ab3 = (char*)smem + ABUF_E * 6;
    unsigned short* wc = smem + WCOP_E;         // 8 shifted reversed-w copies

    const int tid  = threadIdx.x;
    const int lane = tid & 63;
    const int tb   = tid >> 6;                  // 0..3: col quarter

    // ---- block decode: 512 uniform blocks (40 chunks each) ----
    // quad pair pc=0: q {3,0}; pc=1: q {2,1} -> perfectly equal work.
    const int bid  = blockIdx.x;               // 0..511
    const int m    = (bid & 7) + 8 * ((bid >> 3) & 1);
    const int rt   = (bid >> 4) & 15;          // row tile 0..15 (32 rows)
    const int pc   = bid >> 8;                 // pair class
    const int qA   = pc ? 2 : 3;
    const int qB   = pc ? 1 : 0;

    const float* Xb = x   + (size_t)(m * RPH + rt * 32) * SEQ;
    float*       Ob = out + (size_t)(m * RPH + rt * 32) * SEQ;
    const float* wr = wgt  + m * SEQ;
    const float* br = bias + m * SEQ;

    // ---- staging map: thread stages 1 row-slice of the 32-row A tile ----
    const int srow = tid >> 3;                 // 0..31
    const int wsw  = (srow & 7) << 4;
    const int wb0  = srow * 128 + (((tid & 7) * 16) ^ wsw);
    const float* Xp = Xb + (size_t)srow * SEQ + (tid & 7) * 8;

    // ---- issue chunk-0/1 prefetch immediately (hides under prologue) ----
    PF pfA, pfB;
    LOADPF(pfA, 0);
    LOADPF(pfB, 1);

    // ---- phase 1: reversed bf16 weights into abuf-alias ----
    {
        const int t8 = tid * 8;                // 0..2040
        const float* g = wr + (2040 - t8);
        float4 lo = *(const float4*)g;
        float4 hi = *(const float4*)(g + 4);
        uint4 v;
        v.x = f2bf(hi.w) | (f2bf(hi.z) << 16);
        v.y = f2bf(hi.y) | (f2bf(hi.x) << 16);
        v.z = f2bf(lo.w) | (f2bf(lo.z) << 16);
        v.w = f2bf(lo.y) | (f2bf(lo.x) << 16);
        *(uint4*)(smem + 8 + t8) = v;
        if (tid < 21) {                        // guard (8) + pad (160)
            uint4 z = {0u, 0u, 0u, 0u};
            unsigned short* dst = (tid == 0) ? smem
                                 : smem + 8 + 2048 + (tid - 1) * 8;
            *(uint4*)dst = z;
        }
    }
    __syncthreads();

    // ---- phase 2: 8 shifted copies, vectorized: copy_c[i] = wbase[i-c] ----
    #pragma unroll
    for (int c = 0; c < 8; ++c) {
        for (int grp = tid; grp < WSTRIDE / 8; grp += NTH) {
            const int i = grp * 8;
            uint4 g0 = *(const uint4*)(smem + 8 + i - 8);
            uint4 g1 = *(const uint4*)(smem + 8 + i);
            unsigned d[9] = {g0.x, g0.y, g0.z, g0.w,
                             g1.x, g1.y, g1.z, g1.w, 0u};
            const int qd = (16 - 2 * c) >> 2;
            uint4 o;
            if (c & 1) {
                o.x = (d[qd]     >> 16) | (d[qd + 1] << 16);
                o.y = (d[qd + 1] >> 16) | (d[qd + 2] << 16);
                o.z = (d[qd + 2] >> 16) | (d[qd + 3] << 16);
                o.w = (d[qd + 3] >> 16) | (d[qd + 4] << 16);
            } else {
                o.x = d[qd];     o.y = d[qd + 1];
                o.z = d[qd + 2]; o.w = d[qd + 3];
            }
            *(uint4*)(wc + c * WSTRIDE + i) = o;
        }
    }
    __syncthreads();   // wcop ready; wbase alias (abufs) free to overwrite

    // ---- per-lane MFMA constants ----
    const int col_low = lane & 15;
    const int kq      = lane >> 4;
    const int kq16    = kq * 16;
    const int swz     = (col_low & 7) << 4;
    const int cpy     = (col_low + 1) & 7;     // alignment class -> copy id
    const int BcBase  = cpy * WSTRIDE + cpy + 2047 - col_low + 8 * kq;
    const int Arow0   = col_low * 128;
    const int Arow1   = (col_low + 16) * 128;

    // ---- two quads per block: qA (heavy) then qB ----
    for (int h = 0; h < 2; ++h) {
        const int q    = h ? qB : qA;
        const int nch  = 8 * q + 8;            // shared K sweep chunks (of 64)
        const int nchw = 8 * q + 2 * tb + 2;   // this wave's MFMA extent
        const int t0w  = 512 * q + 128 * tb;   // wave's col base
        const unsigned short* wcB = wc + (BcBase - t0w);

        if (h) { LOADPF(pfA, 0); LOADPF(pfB, 1); }  // same rows both quads

        // window prologue: words -7..0 into slots w&15
        bf16x8 bw[16];
        #pragma unroll
        for (int w = -7; w <= 0; ++w)
            bw[w & 15] = *(const bf16x8*)(wcB + 16 * w);

        // seed chunks 0,1 (shared); advance pf to chunks 2,3 (nch >= 8)
        WRITEA(ab0, pfA);
        WRITEA(ab1, pfB);
        LOADPF(pfA, 2);
        LOADPF(pfB, 3);
        asm volatile("s_waitcnt lgkmcnt(0)\n\ts_barrier" ::: "memory");

        f32x4 acc[2][8] = {};
        for (int ch = 0; ch < nch; ch += 4) {  // nch % 8 == 0 always
            SUPER(ch,     0, ab0, ab1, ab2, ab3);
            SUPER(ch + 2, 8, ab2, ab3, ab0, ab1);
        }

        // epilogue: C/D layout col=lane&15, row=(lane>>4)*4+reg
        #pragma unroll
        for (int c = 0; c < 8; ++c) {
            const int colg = t0w + 16 * c + col_low;
            const float bv = br[colg];
            #pragma unroll
            for (int a = 0; a < 2; ++a) {
                const int rowl = 16 * a + 4 * kq;
                #pragma unroll
                for (int rr = 0; rr < 4; ++rr)
                    Ob[(size_t)(rowl + rr) * SEQ + colg] = acc[a][c][rr] + bv;
            }
        }
        // last SUPER's barrier ordered all reads before next quad's seeds.
    }
}

extern "C" void kernel_launch(void* const* d_in, const int* in_sizes, int n_in,
                              void* d_out, int out_size, void* d_ws, size_t ws_size,
                              hipStream_t stream) {
    const float* x  = (const float*)d_in[0];
    const float* w  = (const float*)d_in[1];
    const float* bs = (const float*)d_in[2];
    float* out = (float*)d_out;
    dim3 grid(512);    // 16 heads x 16 row tiles x 2 quad-pair classes
    dim3 block(NTH);
    hipLaunchKernelGGL(mixer_kernel, grid, block, 0, stream, x, w, bs, out);
}

// Round 17
// 41.053 us; speedup vs baseline: 1.0825x; 1.0825x over previous
//
#include <hip/hip_runtime.h>
#include <hip/hip_bf16.h>

#define SEQ    2048
#define NHEAD  16
#define RPH    512          // rows per head = B*D
#define BK     64
#define NTH    256          // 4 waves: wave tb = col quarter of the quad

#define WSTRIDE 2184        // elems per wrev copy; 2184 % 64 == 8 (bank spread)
#define ABUF_E  2048        // elems per A buffer (32 rows x 64 cols bf16)
#define WCOP_E  (8 * ABUF_E)             // wcop after the EIGHT A buffers
#define TOT_E   (WCOP_E + 8 * WSTRIDE)   // 16384 + 17472 = 33856 elems (67712 B)
// wbase staging (guard 0..7, data 8..2055, zero pad 2056..2215) aliases abufs

typedef float  f32x4  __attribute__((ext_vector_type(4)));
typedef __bf16 bf16x8 __attribute__((ext_vector_type(8)));

struct PF { float4 v0, v1; };

__device__ __forceinline__ unsigned f2bf(float f) {
    union { __hip_bfloat16 h; unsigned short u; } cv;
    cv.h = __float2bfloat16(f);
    return (unsigned)cv.u;
}

__device__ __forceinline__ uint4 pack8u(float4 a, float4 b) {
    union { bf16x8 v; uint4 u; } r;
    r.v[0] = (__bf16)a.x; r.v[1] = (__bf16)a.y;
    r.v[2] = (__bf16)a.z; r.v[3] = (__bf16)a.w;
    r.v[4] = (__bf16)b.x; r.v[5] = (__bf16)b.y;
    r.v[6] = (__bf16)b.z; r.v[7] = (__bf16)b.w;
    return r.u;
}

#define MFMA16(a, b, c) __builtin_amdgcn_mfma_f32_16x16x32_bf16((a), (b), (c), 0, 0, 0)

// Load this thread's 1 staged row x 8 cols fp32 of chunk CH
// (block stages 32 rows: tid>>3 = row, (tid&7)*8 = col base).
#define LOADPF(P, CH)                                                         \
  { const float* g_ = Xp + (size_t)(CH) * BK;                                 \
    P.v0 = *(const float4*)g_;                                                \
    P.v1 = *(const float4*)(g_ + 4); }

// Pack+write this thread's staged row-slice into buffer AB (XOR-swizzled).
#define WRITEA(AB, P)  { *(uint4*)((AB) + wb0) = pack8u(P.v0, P.v1); }

// One K=32 step: A frags from shared LDS buf ABC, B words from the sliding
// 16-slot window bw at slot (P + 2*KS - c) & 15 (all compile-time).
#define KSTEPQ(ABC, KS, P)                                                    \
  { const int kb_ = (64 * (KS) + kq16) ^ swz;                                 \
    bf16x8 af0 = *(const bf16x8*)((ABC) + Arow0 + kb_);                       \
    bf16x8 af1 = *(const bf16x8*)((ABC) + Arow1 + kb_);                       \
    acc[0][0] = MFMA16(af0, bw[((P)+2*(KS)-0)&15], acc[0][0]);                \
    acc[1][0] = MFMA16(af1, bw[((P)+2*(KS)-0)&15], acc[1][0]);                \
    acc[0][1] = MFMA16(af0, bw[((P)+2*(KS)-1)&15], acc[0][1]);                \
    acc[1][1] = MFMA16(af1, bw[((P)+2*(KS)-1)&15], acc[1][1]);                \
    acc[0][2] = MFMA16(af0, bw[((P)+2*(KS)-2)&15], acc[0][2]);                \
    acc[1][2] = MFMA16(af1, bw[((P)+2*(KS)-2)&15], acc[1][2]);                \
    acc[0][3] = MFMA16(af0, bw[((P)+2*(KS)-3)&15], acc[0][3]);                \
    acc[1][3] = MFMA16(af1, bw[((P)+2*(KS)-3)&15], acc[1][3]);                \
    acc[0][4] = MFMA16(af0, bw[((P)+2*(KS)-4)&15], acc[0][4]);                \
    acc[1][4] = MFMA16(af1, bw[((P)+2*(KS)-4)&15], acc[1][4]);                \
    acc[0][5] = MFMA16(af0, bw[((P)+2*(KS)-5)&15], acc[0][5]);                \
    acc[1][5] = MFMA16(af1, bw[((P)+2*(KS)-5)&15], acc[1][5]);                \
    acc[0][6] = MFMA16(af0, bw[((P)+2*(KS)-6)&15], acc[0][6]);                \
    acc[1][6] = MFMA16(af1, bw[((P)+2*(KS)-6)&15], acc[1][6]);                \
    acc[0][7] = MFMA16(af0, bw[((P)+2*(KS)-7)&15], acc[0][7]);                \
    acc[1][7] = MFMA16(af1, bw[((P)+2*(KS)-7)&15], acc[1][7]); }

// One SUPERCHUNK = chunks CH, CH+1. Counted-wait pipeline, depth 2 supers:
//   - MFMA chunks CH, CH+1 from C0,C1 (staged 2 supers ago, visibility
//     guaranteed: their writes retired before the previous body's A-reads
//     completed, in-order DS retirement).
//   - THEN stage chunks CH+4, CH+5 into N0,N1 (writes issued LAST).
//   - barrier waits lgkmcnt(2): the 2 fresh writes stay in flight across
//     the barrier; everything older is provably retired.
#define SUPER(CH, P, C0, C1, N0, N1)                                          \
  {                                                                           \
    if ((CH) < nchw) {                                                        \
      __builtin_amdgcn_s_setprio(1);                                          \
      KSTEPQ(C0, 0, P);                                                       \
      bw[((P)+1)&15] = *(const bf16x8*)(wcB + 64 * (CH) + 16);                \
      bw[((P)+2)&15] = *(const bf16x8*)(wcB + 64 * (CH) + 32);                \
      KSTEPQ(C0, 1, P);                                                       \
      __builtin_amdgcn_s_setprio(0);                                          \
    }                                                                         \
    if ((CH) + 1 < nchw) {                                                    \
      bw[((P)+3)&15] = *(const bf16x8*)(wcB + 64 * (CH) + 48);                \
      bw[((P)+4)&15] = *(const bf16x8*)(wcB + 64 * (CH) + 64);                \
      __builtin_amdgcn_s_setprio(1);                                          \
      KSTEPQ(C1, 0, (P) + 4);                                                 \
      bw[((P)+5)&15] = *(const bf16x8*)(wcB + 64 * (CH) + 80);                \
      bw[((P)+6)&15] = *(const bf16x8*)(wcB + 64 * (CH) + 96);                \
      KSTEPQ(C1, 1, (P) + 4);                                                 \
      __builtin_amdgcn_s_setprio(0);                                          \
    }                                                                         \
    if ((CH) + 2 < nchw) {                                                    \
      bw[((P)+7)&15] = *(const bf16x8*)(wcB + 64 * (CH) + 112);               \
      bw[((P)+8)&15] = *(const bf16x8*)(wcB + 64 * (CH) + 128);               \
    }                                                                         \
    WRITEA(N0, pfA);                       /* stage CH+4 (tail: inert) */     \
    WRITEA(N1, pfB);                       /* stage CH+5 (tail: inert) */     \
    if ((CH) + 6 < nch) LOADPF(pfA, (CH) + 6);                                \
    if ((CH) + 7 < nch) LOADPF(pfB, (CH) + 7);                                \
    asm volatile("s_waitcnt lgkmcnt(2)\n\ts_barrier" ::: "memory");           \
  }

__global__ __launch_bounds__(NTH, 2) void mixer_kernel(
    const float* __restrict__ x, const float* __restrict__ wgt,
    const float* __restrict__ bias, float* __restrict__ out)
{
    __shared__ unsigned short smem[TOT_E] __attribute__((aligned(16)));
    char* b0 = (char*)smem;                     // A buffers (chunks mod 8)
    char* b1 = (char*)smem + ABUF_E * 2;
    char* b2 = (char*)smem + ABUF_E * 4;
    char* b3 = (char*)smem + ABUF_E * 6;
    char* b4 = (char*)smem + ABUF_E * 8;
    char* b5 = (char*)smem + ABUF_E * 10;
    char* b6 = (char*)smem + ABUF_E * 12;
    char* b7 = (char*)smem + ABUF_E * 14;
    unsigned short* wc = smem + WCOP_E;         // 8 shifted reversed-w copies

    const int tid  = threadIdx.x;
    const int lane = tid & 63;
    const int tb   = tid >> 6;                  // 0..3: col quarter

    // ---- block decode: 512 uniform blocks (40 chunks each) ----
    // quad pair pc=0: q {3,0}; pc=1: q {2,1} -> perfectly equal work.
    const int bid  = blockIdx.x;               // 0..511
    const int m    = (bid & 7) + 8 * ((bid >> 3) & 1);
    const int rt   = (bid >> 4) & 15;          // row tile 0..15 (32 rows)
    const int pc   = bid >> 8;                 // pair class
    const int qA   = pc ? 2 : 3;
    const int qB   = pc ? 1 : 0;

    const float* Xb = x   + (size_t)(m * RPH + rt * 32) * SEQ;
    float*       Ob = out + (size_t)(m * RPH + rt * 32) * SEQ;
    const float* wr = wgt  + m * SEQ;
    const float* br = bias + m * SEQ;

    // ---- staging map: thread stages 1 row-slice of the 32-row A tile ----
    const int srow = tid >> 3;                 // 0..31
    const int wsw  = (srow & 7) << 4;
    const int wb0  = srow * 128 + (((tid & 7) * 16) ^ wsw);
    const float* Xp = Xb + (size_t)srow * SEQ + (tid & 7) * 8;

    // ---- issue chunk-0/1 prefetch immediately (hides under prologue) ----
    PF pfA, pfB;
    LOADPF(pfA, 0);
    LOADPF(pfB, 1);

    // ---- phase 1: reversed bf16 weights into abuf-alias ----
    {
        const int t8 = tid * 8;                // 0..2040
        const float* g = wr + (2040 - t8);
        float4 lo = *(const float4*)g;
        float4 hi = *(const float4*)(g + 4);
        uint4 v;
        v.x = f2bf(hi.w) | (f2bf(hi.z) << 16);
        v.y = f2bf(hi.y) | (f2bf(hi.x) << 16);
        v.z = f2bf(lo.w) | (f2bf(lo.z) << 16);
        v.w = f2bf(lo.y) | (f2bf(lo.x) << 16);
        *(uint4*)(smem + 8 + t8) = v;
        if (tid < 21) {                        // guard (8) + pad (160)
            uint4 z = {0u, 0u, 0u, 0u};
            unsigned short* dst = (tid == 0) ? smem
                                 : smem + 8 + 2048 + (tid - 1) * 8;
            *(uint4*)dst = z;
        }
    }
    __syncthreads();

    // ---- phase 2: 8 shifted copies, vectorized: copy_c[i] = wbase[i-c] ----
    #pragma unroll
    for (int c = 0; c < 8; ++c) {
        for (int grp = tid; grp < WSTRIDE / 8; grp += NTH) {
            const int i = grp * 8;
            uint4 g0 = *(const uint4*)(smem + 8 + i - 8);
            uint4 g1 = *(const uint4*)(smem + 8 + i);
            unsigned d[9] = {g0.x, g0.y, g0.z, g0.w,
                             g1.x, g1.y, g1.z, g1.w, 0u};
            const int qd = (16 - 2 * c) >> 2;
            uint4 o;
            if (c & 1) {
                o.x = (d[qd]     >> 16) | (d[qd + 1] << 16);
                o.y = (d[qd + 1] >> 16) | (d[qd + 2] << 16);
                o.z = (d[qd + 2] >> 16) | (d[qd + 3] << 16);
                o.w = (d[qd + 3] >> 16) | (d[qd + 4] << 16);
            } else {
                o.x = d[qd];     o.y = d[qd + 1];
                o.z = d[qd + 2]; o.w = d[qd + 3];
            }
            *(uint4*)(wc + c * WSTRIDE + i) = o;
        }
    }
    __syncthreads();   // wcop ready; wbase alias (abufs) free to overwrite

    // ---- per-lane MFMA constants ----
    const int col_low = lane & 15;
    const int kq      = lane >> 4;
    const int kq16    = kq * 16;
    const int swz     = (col_low & 7) << 4;
    const int cpy     = (col_low + 1) & 7;     // alignment class -> copy id
    const int BcBase  = cpy * WSTRIDE + cpy + 2047 - col_low + 8 * kq;
    const int Arow0   = col_low * 128;
    const int Arow1   = (col_low + 16) * 128;

    // ---- two quads per block: qA (heavy) then qB ----
    for (int h = 0; h < 2; ++h) {
        const int q    = h ? qB : qA;
        const int nch  = 8 * q + 8;            // shared K sweep chunks (of 64)
        const int nchw = 8 * q + 2 * tb + 2;   // this wave's MFMA extent
        const int t0w  = 512 * q + 128 * tb;   // wave's col base
        const unsigned short* wcB = wc + (BcBase - t0w);

        if (h) { LOADPF(pfA, 0); LOADPF(pfB, 1); }  // same rows both quads

        // window prologue: words -7..0 into slots w&15
        bf16x8 bw[16];
        #pragma unroll
        for (int w = -7; w <= 0; ++w)
            bw[w & 15] = *(const bf16x8*)(wcB + 16 * w);

        // seed superchunks 0,1 (chunks 0..3); pf -> chunks 4,5 (nch >= 8)
        WRITEA(b0, pfA);
        WRITEA(b1, pfB);
        LOADPF(pfA, 2);
        LOADPF(pfB, 3);
        WRITEA(b2, pfA);
        WRITEA(b3, pfB);
        LOADPF(pfA, 4);
        LOADPF(pfB, 5);
        asm volatile("s_waitcnt lgkmcnt(0)\n\ts_barrier" ::: "memory");

        f32x4 acc[2][8] = {};
        for (int ch = 0; ch < nch; ch += 8) {  // nch % 8 == 0 always
            SUPER(ch,     0, b0, b1, b4, b5);
            SUPER(ch + 2, 8, b2, b3, b6, b7);
            SUPER(ch + 4, 0, b4, b5, b0, b1);
            SUPER(ch + 6, 8, b6, b7, b2, b3);
        }

        // epilogue: C/D layout col=lane&15, row=(lane>>4)*4+reg
        #pragma unroll
        for (int c = 0; c < 8; ++c) {
            const int colg = t0w + 16 * c + col_low;
            const float bv = br[colg];
            #pragma unroll
            for (int a = 0; a < 2; ++a) {
                const int rowl = 16 * a + 4 * kq;
                #pragma unroll
                for (int rr = 0; rr < 4; ++rr)
                    Ob[(size_t)(rowl + rr) * SEQ + colg] = acc[a][c][rr] + bv;
            }
        }
        // next quad's prologue barrier (lgkmcnt 0) drains any in-flight
        // writes before its bodies read the reseeded buffers.
    }
}

extern "C" void kernel_launch(void* const* d_in, const int* in_sizes, int n_in,
                              void* d_out, int out_size, void* d_ws, size_t ws_size,
                              hipStream_t stream) {
    const float* x  = (const float*)d_in[0];
    const float* w  = (const float*)d_in[1];
    const float* bs = (const float*)d_in[2];
    float* out = (float*)d_out;
    dim3 grid(512);    // 16 heads x 16 row tiles x 2 quad-pair classes
    dim3 block(NTH);
    hipLaunchKernelGGL(mixer_kernel, grid, block, 0, stream, x, w, bs, out);
}